// Round 12
// baseline (295.325 us; speedup 1.0000x reference)
//
#include <hip/hip_runtime.h>
#include <hip/hip_bf16.h>

#define N_NODES 50000
#define N_EDGES 300000
#define E_TOT   350000   /* edges + self loops */
#define N_GRAPHS 256
#define F_IN 78
#define H1 10
#define D1 780           /* H1*F_H1 */
#define F_OUT 128
#define KP 800           /* K padded for MFMA gemm2 (780 -> 800) */
#define K1P 96           /* K padded for MFMA agg1 phase2 (78 -> 96) */
#define O1P 808          /* out1 tile row stride (bank-conflict pad) */
#define H2P 132          /* h2 tile row stride (bank-conflict pad) */
#define XROW 39          /* bf16 x row = 39 packed uints */
#define NEG_SLOPE 0.2f
#define NB 196           /* ceil(50000/256) */

typedef float v4f __attribute__((ext_vector_type(4)));
typedef short v8s __attribute__((ext_vector_type(8)));

__device__ __forceinline__ int src_of(int e, const int* __restrict__ ei) {
  return (e < N_EDGES) ? ei[e] : (e - N_EDGES);
}
__device__ __forceinline__ int dst_of(int e, const int* __restrict__ ei) {
  return (e < N_EDGES) ? ei[N_EDGES + e] : (e - N_EDGES);
}
__device__ __forceinline__ float bf2f(unsigned short u) {
  return __uint_as_float(((unsigned int)u) << 16);
}
__device__ __forceinline__ unsigned short f2bf(float f) {
  __hip_bfloat16 b = __float2bfloat16(f);
  return *reinterpret_cast<unsigned short*>(&b);
}

/* ---------------- CSR build: degree, scan, scatter ---------------- */

__global__ void k_deg(const int* __restrict__ ei, int* __restrict__ deg) {
  int e = blockIdx.x * 256 + threadIdx.x;
  if (e >= E_TOT) return;
  atomicAdd(&deg[dst_of(e, ei)], 1);
}

__global__ void k_scan1(const int* __restrict__ deg, int* __restrict__ part) {
  __shared__ int s[256];
  int t = threadIdx.x;
  int i = blockIdx.x * 256 + t;
  s[t] = (i < N_NODES) ? deg[i] : 0;
  __syncthreads();
  for (int d = 128; d > 0; d >>= 1) {
    if (t < d) s[t] += s[t + d];
    __syncthreads();
  }
  if (t == 0) part[blockIdx.x] = s[0];
}

__global__ void k_scan2(const int* __restrict__ part, int* __restrict__ ppref) {
  if (threadIdx.x == 0) {
    int run = 0;
    for (int i = 0; i < NB; ++i) { ppref[i] = run; run += part[i]; }
  }
}

__global__ void k_scan3(const int* __restrict__ deg, const int* __restrict__ ppref,
                        int* __restrict__ offs, int* __restrict__ cursor) {
  __shared__ int s[256];
  int t = threadIdx.x;
  int i = blockIdx.x * 256 + t;
  int v = (i < N_NODES) ? deg[i] : 0;
  s[t] = v;
  __syncthreads();
  for (int d = 1; d < 256; d <<= 1) {
    int u = (t >= d) ? s[t - d] : 0;
    __syncthreads();
    s[t] += u;
    __syncthreads();
  }
  int excl = s[t] - v;
  if (i < N_NODES) {
    int off = ppref[blockIdx.x] + excl;
    offs[i] = off;
    cursor[i] = off;
  }
}

__global__ void k_scatter(const int* __restrict__ ei, int* __restrict__ cursor,
                          int* __restrict__ src_s, int* __restrict__ dst_s) {
  int e = blockIdx.x * 256 + threadIdx.x;
  if (e >= E_TOT) return;
  int s = src_of(e, ei);
  int d = dst_of(e, ei);
  int pos = atomicAdd(&cursor[d], 1);
  src_s[pos] = s;
  dst_s[pos] = d;
}

/* ---- x fp32 -> bf16 table (row = 39 packed uints) ---- */

__global__ void k_xb(const float* __restrict__ x, __hip_bfloat16* __restrict__ xb) {
  int i = blockIdx.x * 256 + threadIdx.x;
  if (i >= N_NODES * F_IN) return;
  xb[i] = __float2bfloat16(x[i]);
}

/* ---- was[k,h] = sum_f W1[k, h*78+f] * a_src1[h*78+f]; same for wad ---- */

__global__ void k_prep(const float* __restrict__ W1, const float* __restrict__ as1,
                       const float* __restrict__ ad1, float* __restrict__ was,
                       float* __restrict__ wad) {
  int i = blockIdx.x * 256 + threadIdx.x;
  if (i >= F_IN * H1) return;
  int k = i / H1, h = i - k * H1;
  const float* wrow = W1 + (size_t)k * D1 + h * 78;
  const float* ar = as1 + h * 78;
  const float* br = ad1 + h * 78;
  float s = 0.f, d = 0.f;
  for (int f = 0; f < 78; ++f) {
    float w = wrow[f];
    s = fmaf(w, ar[f], s);
    d = fmaf(w, br[f], d);
  }
  was[i] = s;  /* layout [k][h] */
  wad[i] = d;
}

/* ---- als1[n,h] = x[n,:] . was[:,h] ; ald1 likewise (LDS-staged) ---- */

__global__ __launch_bounds__(320) void k_logits1(const float* __restrict__ x,
                                                 const float* __restrict__ was,
                                                 const float* __restrict__ wad,
                                                 float* __restrict__ als,
                                                 float* __restrict__ ald) {
  __shared__ float xs[32][81];
  __shared__ float wl[D1], wl2[D1];
  int tid = threadIdx.x;
  int n0 = blockIdx.x * 32;
  for (int i = tid; i < 32 * F_IN; i += 320) {
    int r = i / F_IN, k = i - r * F_IN;
    int n = n0 + r;
    xs[r][k] = (n < N_NODES) ? x[(size_t)n * F_IN + k] : 0.f;
  }
  for (int i = tid; i < D1; i += 320) { wl[i] = was[i]; wl2[i] = wad[i]; }
  __syncthreads();
  int r = tid / 10, h = tid - r * 10;
  int n = n0 + r;
  float s = 0.f, d = 0.f;
  for (int k = 0; k < F_IN; ++k) {
    float xv = xs[r][k];
    s = fmaf(xv, wl[k * 10 + h], s);
    d = fmaf(xv, wl2[k * 10 + h], d);
  }
  if (n < N_NODES) { als[n * 10 + h] = s; ald[n * 10 + h] = d; }
}

/* ---- edge-parallel raw weights, layer 1: w1[pos,h] = exp(leaky(...)) ---- */

__global__ void k_w1e(const float* __restrict__ als1, const float* __restrict__ ald1,
                      const int* __restrict__ src_s, const int* __restrict__ dst_s,
                      float* __restrict__ w1) {
  int i = blockIdx.x * 256 + threadIdx.x;
  if (i >= E_TOT * H1) return;
  int pos = i / H1, h = i - pos * H1;
  float v = als1[src_s[pos] * H1 + h] + ald1[dst_s[pos] * H1 + h];
  v = (v > 0.f) ? v : NEG_SLOPE * v;
  w1[i] = __expf(v);
}

/* ---- W1 [78][780] fp32 -> W1T [800][96] bf16: W1T[c][k] = W1[k][c] ---- */

__global__ void k_w1t(const float* __restrict__ W1, __hip_bfloat16* __restrict__ T) {
  int i = blockIdx.x * 256 + threadIdx.x;
  if (i >= 800 * K1P) return;
  int r = i / K1P, k = i - r * K1P;
  float v = (r < D1 && k < F_IN) ? W1[(size_t)k * D1 + r] : 0.f;
  T[i] = __float2bfloat16(v);
}

/* ---- W2 [780][128] fp32 -> W2T [128][800] bf16 (zero-padded K) ---- */

__global__ void k_w2t(const float* __restrict__ W2, __hip_bfloat16* __restrict__ Bt) {
  int i = blockIdx.x * 256 + threadIdx.x;
  if (i >= F_OUT * KP) return;
  int c = i / KP, k = i - c * KP;
  float v = (k < D1) ? W2[(size_t)k * F_OUT + c] : 0.f;
  Bt[i] = __float2bfloat16(v);
}

/* ==== MEGA-FUSED layer 1 + layer-2 projection + layer-2 logits ====
   ph1: weighted bf16-x gather, ONE packed-uint request per edge
        (lane l<39 holds features 2l,2l+1; lane 39 = ones-column -> Σw)
   ph2: per-head MFMA xagg @ W1T + bias + ELU -> out1 tile (LDS)
   ph3: out1 tile @ W2T MFMA -> h2 bf16 global + LDS
   ph4: als2/ald2 from LDS h2 tile.  out1 never touches HBM. ---- */

__global__ __launch_bounds__(512, 4) void k_l12(const __hip_bfloat16* __restrict__ xb16,
                                                const float* __restrict__ w1,
                                                const int* __restrict__ src_s,
                                                const int* __restrict__ offs,
                                                const int* __restrict__ deg,
                                                const __hip_bfloat16* __restrict__ W1T,
                                                const float* __restrict__ b1,
                                                const __hip_bfloat16* __restrict__ W2T,
                                                const float* __restrict__ a_src2,
                                                const float* __restrict__ a_dst2,
                                                __hip_bfloat16* __restrict__ h2b,
                                                float* __restrict__ als2,
                                                float* __restrict__ ald2) {
  __shared__ __align__(16) unsigned char lds[34304];
  /* overlay 1 (ph1/ph2 in):  xagg bf16 [H1][16][104]        = 33,280 B */
  /* overlay 2 (ph2 out/ph3 in): out1t bf16 [16][808]        = 25,856 B */
  /* overlay 3 (ph3 out/ph4 in): h2t fp32 [16][132] at 25856 =  8,448 B */
  __hip_bfloat16* xbb = (__hip_bfloat16*)lds;
  __hip_bfloat16* out1t = (__hip_bfloat16*)lds;
  float* h2t = (float*)(lds + 25856);
#define XB(h, g, k) xbb[((h) * 16 + (g)) * 104 + (k)]

  int tid = threadIdx.x, wid = tid >> 6, lane = tid & 63;
  int n0 = blockIdx.x * 16;
  int col16 = lane & 15, kq = (lane >> 4) * 8;

  /* zero xagg (covers k 78..103 pad + unwritten lanes) */
  {
    unsigned int* p = (unsigned int*)lds;
    for (int i = tid; i < H1 * 16 * 52; i += 512) p[i] = 0u;
  }
  __syncthreads();

  /* ---- phase 1: per-wave weighted gather, packed-uint loads ---- */
  const unsigned int* xu = (const unsigned int*)xb16;
  bool ldl = lane < XROW;
  const unsigned int onesu = 0x00003F80u;  /* lo=1.0f (bf16), hi=0 */
  #pragma unroll
  for (int rep = 0; rep < 2; ++rep) {
    int g = wid * 2 + rep;
    int n = n0 + g;
    int o = __builtin_amdgcn_readfirstlane(offs[n]);
    int d = __builtin_amdgcn_readfirstlane(deg[n]);
    float accLo[H1], accHi[H1];
    #pragma unroll
    for (int h = 0; h < H1; ++h) { accLo[h] = 0.f; accHi[h] = 0.f; }

    int j = 0;
    for (; j + 4 <= d; j += 4) {
      int e0 = o + j;
      int s0 = src_s[e0], s1 = src_s[e0 + 1], s2 = src_s[e0 + 2], s3 = src_s[e0 + 3];
      unsigned int u0 = ldl ? xu[(size_t)s0 * XROW + lane] : onesu;
      unsigned int u1 = ldl ? xu[(size_t)s1 * XROW + lane] : onesu;
      unsigned int u2 = ldl ? xu[(size_t)s2 * XROW + lane] : onesu;
      unsigned int u3 = ldl ? xu[(size_t)s3 * XROW + lane] : onesu;
      float lo0 = __uint_as_float(u0 << 16), hi0 = __uint_as_float(u0 & 0xFFFF0000u);
      float lo1 = __uint_as_float(u1 << 16), hi1 = __uint_as_float(u1 & 0xFFFF0000u);
      float lo2 = __uint_as_float(u2 << 16), hi2 = __uint_as_float(u2 & 0xFFFF0000u);
      float lo3 = __uint_as_float(u3 << 16), hi3 = __uint_as_float(u3 & 0xFFFF0000u);
      const float* wp = w1 + (size_t)e0 * H1;   /* 40 contiguous, uniform */
      #pragma unroll
      for (int h = 0; h < H1; ++h) {
        float wa = wp[h], wb = wp[10 + h], wc = wp[20 + h], wd = wp[30 + h];
        accLo[h] = fmaf(wa, lo0, accLo[h]);
        accLo[h] = fmaf(wb, lo1, accLo[h]);
        accLo[h] = fmaf(wc, lo2, accLo[h]);
        accLo[h] = fmaf(wd, lo3, accLo[h]);
        accHi[h] = fmaf(wa, hi0, accHi[h]);
        accHi[h] = fmaf(wb, hi1, accHi[h]);
        accHi[h] = fmaf(wc, hi2, accHi[h]);
        accHi[h] = fmaf(wd, hi3, accHi[h]);
      }
    }
    for (; j < d; ++j) {
      int e0 = o + j;
      int s0 = src_s[e0];
      unsigned int u0 = ldl ? xu[(size_t)s0 * XROW + lane] : onesu;
      float lo0 = __uint_as_float(u0 << 16), hi0 = __uint_as_float(u0 & 0xFFFF0000u);
      const float* wp = w1 + (size_t)e0 * H1;
      #pragma unroll
      for (int h = 0; h < H1; ++h) {
        float wa = wp[h];
        accLo[h] = fmaf(wa, lo0, accLo[h]);
        accHi[h] = fmaf(wa, hi0, accHi[h]);
      }
    }
    #pragma unroll
    for (int h = 0; h < H1; ++h) {
      float inv = 1.f / __shfl(accLo[h], XROW);   /* Σw in lane 39 lo */
      if (ldl) {
        unsigned int pk = (unsigned int)f2bf(accLo[h] * inv)
                        | ((unsigned int)f2bf(accHi[h] * inv) << 16);
        /* features 2*lane, 2*lane+1 -> u32 at byte offset 4*lane */
        *reinterpret_cast<unsigned int*>(
            reinterpret_cast<unsigned char*>(&XB(h, g, 0)) + 4 * lane) = pk;
      }
    }
  }
  __syncthreads();

  /* ---- phase 2: 50 units (h, nt); static res indexing (no scratch) ---- */
  const unsigned short* Bp1 = (const unsigned short*)W1T;
  v4f res[7];
  #pragma unroll
  for (int i = 0; i < 7; ++i) {
    int u = wid + i * 8;
    v4f acc = (v4f){0.f, 0.f, 0.f, 0.f};
    if (u < 50) {
      int h = u / 5, nt = u - (u / 5) * 5;
      #pragma unroll
      for (int kt = 0; kt < 3; ++kt) {
        v8s a = *reinterpret_cast<const v8s*>(&XB(h, col16, kt * 32 + kq));
        v8s b = *reinterpret_cast<const v8s*>(
            &Bp1[(size_t)(h * 78 + nt * 16 + col16) * K1P + kt * 32 + kq]);
        acc = __builtin_amdgcn_mfma_f32_16x16x32_bf16(a, b, acc, 0, 0, 0);
      }
    }
    res[i] = acc;
  }
  __syncthreads();   /* all xagg reads done; LDS now reusable as out1t */

  /* tail-zero out1t cols 780..807 (28 cols = 14 uints per node) */
  if (tid < 224) {
    int node = tid / 14, cc = (tid - node * 14) * 2;
    *(unsigned int*)&out1t[node * O1P + 780 + cc] = 0u;
  }
  /* store phase-2 results (bias + ELU) into out1t */
  #pragma unroll
  for (int i = 0; i < 7; ++i) {
    int u = wid + i * 8;
    if (u < 50) {
      int h = u / 5, nt = u - (u / 5) * 5;
      v4f acc = res[i];
      int cl = nt * 16 + col16;
      if (cl < 78) {
        int c = h * 78 + cl;
        float bv = b1[c];
        #pragma unroll
        for (int r = 0; r < 4; ++r) {
          int node = (lane >> 4) * 4 + r;
          float v = acc[r] + bv;
          v = (v > 0.f) ? v : expm1f(v);  /* ELU */
          out1t[node * O1P + c] = __float2bfloat16(v);
        }
      }
    }
  }
  __syncthreads();

  /* ---- phase 3: h2 tile = out1t @ W2T^T; 1 unit (16 cols) per wave ---- */
  const unsigned short* Bp2 = (const unsigned short*)W2T;
  v4f acc3 = (v4f){0.f, 0.f, 0.f, 0.f};
  #pragma unroll 5
  for (int kt = 0; kt < 25; ++kt) {
    int k = kt * 32 + kq;
    v8s a = *reinterpret_cast<const v8s*>(&out1t[col16 * O1P + k]);
    v8s b = *reinterpret_cast<const v8s*>(&Bp2[(size_t)(wid * 16 + col16) * KP + k]);
    acc3 = __builtin_amdgcn_mfma_f32_16x16x32_bf16(a, b, acc3, 0, 0, 0);
  }
  {
    int col = wid * 16 + col16;
    #pragma unroll
    for (int r = 0; r < 4; ++r) {
      int node = (lane >> 4) * 4 + r;
      h2b[(size_t)(n0 + node) * F_OUT + col] = __float2bfloat16(acc3[r]);
      h2t[node * H2P + col] = acc3[r];
    }
  }
  __syncthreads();

  /* ---- phase 4: layer-2 logits for this block's 16 nodes ---- */
  #pragma unroll
  for (int rep = 0; rep < 2; ++rep) {
    int nn = wid * 2 + rep;
    float v0 = h2t[nn * H2P + lane], v1 = h2t[nn * H2P + 64 + lane];
    float s = v0 * a_src2[lane] + v1 * a_src2[64 + lane];
    float dd = v0 * a_dst2[lane] + v1 * a_dst2[64 + lane];
    #pragma unroll
    for (int off = 32; off > 0; off >>= 1) {
      s += __shfl_down(s, off);
      dd += __shfl_down(dd, off);
    }
    if (lane == 0) { als2[n0 + nn] = s; ald2[n0 + nn] = dd; }
  }
#undef XB
}

/* ---- layer 2 aggregation (fused edge-weights + bf16 h2 gathers)
   + bias + ReLU + fused graph max-pool ---- */

__global__ __launch_bounds__(512) void k_agg2f(const __hip_bfloat16* __restrict__ h2b,
                                               const float* __restrict__ als2,
                                               const float* __restrict__ ald2,
                                               const int* __restrict__ src_s,
                                               const int* __restrict__ offs,
                                               const int* __restrict__ deg,
                                               const float* __restrict__ b2,
                                               const int* __restrict__ batch,
                                               unsigned int* __restrict__ g) {
  int tid = threadIdx.x;
  int n = blockIdx.x * 4 + (tid >> 7);
  int f = tid & 127;
  int o = __builtin_amdgcn_readfirstlane(offs[n]);
  int d = __builtin_amdgcn_readfirstlane(deg[n]);
  float aldn = ald2[n];
  const unsigned short* hu = (const unsigned short*)h2b;
  float acc = 0.f, ssum = 0.f;
  int j = 0;
  for (; j + 4 <= d; j += 4) {
    float wq[4], hq[4];
    #pragma unroll
    for (int q = 0; q < 4; ++q) {
      int e = o + j + q;
      int sb = src_s[e];
      float v = als2[sb] + aldn;
      v = (v > 0.f) ? v : NEG_SLOPE * v;
      wq[q] = __expf(v);
      hq[q] = bf2f(hu[(size_t)sb * F_OUT + f]);
    }
    #pragma unroll
    for (int q = 0; q < 4; ++q) {
      ssum += wq[q];
      acc = fmaf(wq[q], hq[q], acc);
    }
  }
  for (; j < d; ++j) {
    int e = o + j;
    int sb = src_s[e];
    float v = als2[sb] + aldn;
    v = (v > 0.f) ? v : NEG_SLOPE * v;
    float w = __expf(v);
    ssum += w;
    acc = fmaf(w, bf2f(hu[(size_t)sb * F_OUT + f]), acc);
  }
  float v = fmaxf(acc / ssum + b2[f], 0.f);
  int gc = __builtin_amdgcn_readfirstlane(batch[n]);
  atomicMax(&g[gc * F_OUT + f], __float_as_uint(v));
}

/* ---------------- fc ---------------- */

__global__ __launch_bounds__(128) void k_fc(const float* __restrict__ g,
                                            const float* __restrict__ fc_w,
                                            const float* __restrict__ fc_b,
                                            float* __restrict__ out) {
  int b = blockIdx.x, c = threadIdx.x;
  const float* gr = g + (size_t)b * F_OUT;
  float acc = 0.f;
  for (int k = 0; k < F_OUT; ++k) acc = fmaf(gr[k], fc_w[k * F_OUT + c], acc);
  float v = acc + fc_b[c];
  out[(size_t)b * F_OUT + c] = fmaxf(v, 0.f);
}

/* ---------------- launch ---------------- */

extern "C" void kernel_launch(void* const* d_in, const int* in_sizes, int n_in,
                              void* d_out, int out_size, void* d_ws, size_t ws_size,
                              hipStream_t stream) {
  const float* x      = (const float*)d_in[0];
  const int*   ei     = (const int*)  d_in[1];
  const int*   batch  = (const int*)  d_in[2];
  const float* W1     = (const float*)d_in[3];
  const float* a_src1 = (const float*)d_in[4];
  const float* a_dst1 = (const float*)d_in[5];
  const float* b1     = (const float*)d_in[6];
  const float* W2     = (const float*)d_in[7];
  const float* a_src2 = (const float*)d_in[8];
  const float* a_dst2 = (const float*)d_in[9];
  const float* b2     = (const float*)d_in[10];
  const float* fc_w   = (const float*)d_in[11];
  const float* fc_b   = (const float*)d_in[12];
  float* out = (float*)d_out;

  float* ws = (float*)d_ws;
  __hip_bfloat16* h2b = (__hip_bfloat16*)ws;      /* 6,400,000 bf16 = 3.2M fl */
  float* als1 = ws + 3200000;             /*   500,000 */
  float* ald1 = ws + 3700000;             /*   500,000 */
  float* als2 = ws + 4200000;             /*    50,000 */
  float* ald2 = ws + 4250000;             /*    50,000 */
  float* g    = ws + 4300000;             /*    32,768 */
  float* was  = ws + 4333000;             /*       780 */
  float* wad  = ws + 4334000;             /*       780 */
  __hip_bfloat16* W2T = (__hip_bfloat16*)(ws + 4335000);   /* 102,400 bf16 */
  __hip_bfloat16* W1T = (__hip_bfloat16*)(ws + 4387000);   /*  76,800 bf16 */
  __hip_bfloat16* xb16 = (__hip_bfloat16*)(ws + 4426000);  /* 3,900,000 bf16 */
  float* w1   = ws + 6377000;             /* 3,500,000 */
  int* ib     = (int*)(ws + 9877000);
  int* deg    = ib;                        /*  50,000 */
  int* offs   = ib + 50000;
  int* cursor = ib + 100000;
  int* src_s  = ib + 150000;               /* 350,000 */
  int* dst_s  = ib + 500000;               /* 350,000 */
  int* part   = ib + 850000;               /* 196 */
  int* ppref  = ib + 850224;               /* 196 */

  /* CSR build */
  hipMemsetAsync(deg, 0, N_NODES * sizeof(int), stream);
  k_deg<<<(E_TOT + 255) / 256, 256, 0, stream>>>(ei, deg);
  k_scan1<<<NB, 256, 0, stream>>>(deg, part);
  k_scan2<<<1, 64, 0, stream>>>(part, ppref);
  k_scan3<<<NB, 256, 0, stream>>>(deg, ppref, offs, cursor);
  k_scatter<<<(E_TOT + 255) / 256, 256, 0, stream>>>(ei, cursor, src_s, dst_s);

  /* weights / tables prep */
  k_prep<<<4, 256, 0, stream>>>(W1, a_src1, a_dst1, was, wad);
  k_w1t<<<(800 * K1P + 255) / 256, 256, 0, stream>>>(W1, W1T);
  k_w2t<<<(F_OUT * KP + 255) / 256, 256, 0, stream>>>(W2, W2T);
  k_xb<<<(N_NODES * F_IN + 255) / 256, 256, 0, stream>>>(x, xb16);
  /* zero pool accumulator (used by fused agg2f) */
  hipMemsetAsync(g, 0, N_GRAPHS * F_OUT * sizeof(float), stream);

  /* layer 1 logits + edge weights */
  k_logits1<<<(N_NODES + 31) / 32, 320, 0, stream>>>(x, was, wad, als1, ald1);
  k_w1e<<<(E_TOT * H1 + 255) / 256, 256, 0, stream>>>(als1, ald1, src_s, dst_s, w1);

  /* mega-fused: agg1 + out1 + gemm2 + al2 */
  k_l12<<<N_NODES / 16, 512, 0, stream>>>(xb16, w1, src_s, offs, deg, W1T, b1,
                                          W2T, a_src2, a_dst2, h2b, als2, ald2);

  /* layer 2 (edge weights fused into agg2f) */
  k_agg2f<<<(N_NODES + 3) / 4, 512, 0, stream>>>(h2b, als2, ald2, src_s, offs, deg,
                                                 b2, batch, (unsigned int*)g);

  /* fc */
  k_fc<<<N_GRAPHS, F_OUT, 0, stream>>>(g, fc_w, fc_b, out);
}

// Round 13
// 267.135 us; speedup vs baseline: 1.1055x; 1.1055x over previous
//
#include <hip/hip_runtime.h>
#include <hip/hip_bf16.h>

#define N_NODES 50000
#define N_EDGES 300000
#define E_TOT   350000   /* edges + self loops */
#define N_GRAPHS 256
#define F_IN 78
#define H1 10
#define D1 780           /* H1*F_H1 */
#define F_OUT 128
#define KP 800           /* K padded for MFMA gemm2 (780 -> 800) */
#define K1P 96           /* K padded for MFMA agg1 phase2 (78 -> 96) */
#define NEG_SLOPE 0.2f
#define NB 196           /* ceil(50000/256) */

typedef float v4f __attribute__((ext_vector_type(4)));
typedef short v8s __attribute__((ext_vector_type(8)));

__device__ __forceinline__ int src_of(int e, const int* __restrict__ ei) {
  return (e < N_EDGES) ? ei[e] : (e - N_EDGES);
}
__device__ __forceinline__ int dst_of(int e, const int* __restrict__ ei) {
  return (e < N_EDGES) ? ei[N_EDGES + e] : (e - N_EDGES);
}

/* ---------------- CSR build: degree, scan, scatter ---------------- */

__global__ void k_deg(const int* __restrict__ ei, int* __restrict__ deg) {
  int e = blockIdx.x * 256 + threadIdx.x;
  if (e >= E_TOT) return;
  atomicAdd(&deg[dst_of(e, ei)], 1);
}

__global__ void k_scan1(const int* __restrict__ deg, int* __restrict__ part) {
  __shared__ int s[256];
  int t = threadIdx.x;
  int i = blockIdx.x * 256 + t;
  s[t] = (i < N_NODES) ? deg[i] : 0;
  __syncthreads();
  for (int d = 128; d > 0; d >>= 1) {
    if (t < d) s[t] += s[t + d];
    __syncthreads();
  }
  if (t == 0) part[blockIdx.x] = s[0];
}

__global__ void k_scan2(const int* __restrict__ part, int* __restrict__ ppref) {
  if (threadIdx.x == 0) {
    int run = 0;
    for (int i = 0; i < NB; ++i) { ppref[i] = run; run += part[i]; }
  }
}

__global__ void k_scan3(const int* __restrict__ deg, const int* __restrict__ ppref,
                        int* __restrict__ offs, int* __restrict__ cursor) {
  __shared__ int s[256];
  int t = threadIdx.x;
  int i = blockIdx.x * 256 + t;
  int v = (i < N_NODES) ? deg[i] : 0;
  s[t] = v;
  __syncthreads();
  for (int d = 1; d < 256; d <<= 1) {
    int u = (t >= d) ? s[t - d] : 0;
    __syncthreads();
    s[t] += u;
    __syncthreads();
  }
  int excl = s[t] - v;
  if (i < N_NODES) {
    int off = ppref[blockIdx.x] + excl;
    offs[i] = off;
    cursor[i] = off;
  }
}

__global__ void k_scatter(const int* __restrict__ ei, int* __restrict__ cursor,
                          int* __restrict__ src_s, int* __restrict__ dst_s) {
  int e = blockIdx.x * 256 + threadIdx.x;
  if (e >= E_TOT) return;
  int s = src_of(e, ei);
  int d = dst_of(e, ei);
  int pos = atomicAdd(&cursor[d], 1);
  src_s[pos] = s;
  dst_s[pos] = d;
}

/* ---- was[k,h] = sum_f W1[k, h*78+f] * a_src1[h*78+f]; same for wad ---- */

__global__ void k_prep(const float* __restrict__ W1, const float* __restrict__ as1,
                       const float* __restrict__ ad1, float* __restrict__ was,
                       float* __restrict__ wad) {
  int i = blockIdx.x * 256 + threadIdx.x;
  if (i >= F_IN * H1) return;
  int k = i / H1, h = i - k * H1;
  const float* wrow = W1 + (size_t)k * D1 + h * 78;
  const float* ar = as1 + h * 78;
  const float* br = ad1 + h * 78;
  float s = 0.f, d = 0.f;
  for (int f = 0; f < 78; ++f) {
    float w = wrow[f];
    s = fmaf(w, ar[f], s);
    d = fmaf(w, br[f], d);
  }
  was[i] = s;  /* layout [k][h] */
  wad[i] = d;
}

/* ---- als1[n,h] = x[n,:] . was[:,h] ; ald1 likewise (LDS-staged) ---- */

__global__ __launch_bounds__(320) void k_logits1(const float* __restrict__ x,
                                                 const float* __restrict__ was,
                                                 const float* __restrict__ wad,
                                                 float* __restrict__ als,
                                                 float* __restrict__ ald) {
  __shared__ float xs[32][81];
  __shared__ float wl[D1], wl2[D1];
  int tid = threadIdx.x;
  int n0 = blockIdx.x * 32;
  for (int i = tid; i < 32 * F_IN; i += 320) {
    int r = i / F_IN, k = i - r * F_IN;
    int n = n0 + r;
    xs[r][k] = (n < N_NODES) ? x[(size_t)n * F_IN + k] : 0.f;
  }
  for (int i = tid; i < D1; i += 320) { wl[i] = was[i]; wl2[i] = wad[i]; }
  __syncthreads();
  int r = tid / 10, h = tid - r * 10;
  int n = n0 + r;
  float s = 0.f, d = 0.f;
  for (int k = 0; k < F_IN; ++k) {
    float xv = xs[r][k];
    s = fmaf(xv, wl[k * 10 + h], s);
    d = fmaf(xv, wl2[k * 10 + h], d);
  }
  if (n < N_NODES) { als[n * 10 + h] = s; ald[n * 10 + h] = d; }
}

/* ---- edge-parallel raw weights, layer 1: w1[pos,h] = exp(leaky(...)) ---- */

__global__ void k_w1e(const float* __restrict__ als1, const float* __restrict__ ald1,
                      const int* __restrict__ src_s, const int* __restrict__ dst_s,
                      float* __restrict__ w1) {
  int i = blockIdx.x * 256 + threadIdx.x;
  if (i >= E_TOT * H1) return;
  int pos = i / H1, h = i - pos * H1;
  float v = als1[src_s[pos] * H1 + h] + ald1[dst_s[pos] * H1 + h];
  v = (v > 0.f) ? v : NEG_SLOPE * v;
  w1[i] = __expf(v);
}

/* ---- W1 [78][780] fp32 -> W1T [800][96] bf16: W1T[c][k] = W1[k][c] ---- */

__global__ void k_w1t(const float* __restrict__ W1, __hip_bfloat16* __restrict__ T) {
  int i = blockIdx.x * 256 + threadIdx.x;
  if (i >= 800 * K1P) return;
  int r = i / K1P, k = i - r * K1P;
  float v = (r < D1 && k < F_IN) ? W1[(size_t)k * D1 + r] : 0.f;
  T[i] = __float2bfloat16(v);
}

/* ---- W2 [780][128] fp32 -> W2T [128][800] bf16 (zero-padded K) ---- */

__global__ void k_w2t(const float* __restrict__ W2, __hip_bfloat16* __restrict__ Bt) {
  int i = blockIdx.x * 256 + threadIdx.x;
  if (i >= F_OUT * KP) return;
  int c = i / KP, k = i - c * KP;
  float v = (k < D1) ? W2[(size_t)k * F_OUT + c] : 0.f;
  Bt[i] = __float2bfloat16(v);
}

/* ==== MEGA-FUSED layer 1 + layer-2 projection + layer-2 logits ====
   (exact R9 structure: fp32 x gather, dynamic res loop, stride-800 out1t,
    fp32 h2 + LDS h2t) ---- */

__global__ __launch_bounds__(512, 4) void k_l12(const float* __restrict__ x,
                                                const float* __restrict__ w1,
                                                const int* __restrict__ src_s,
                                                const int* __restrict__ offs,
                                                const int* __restrict__ deg,
                                                const __hip_bfloat16* __restrict__ W1T,
                                                const float* __restrict__ b1,
                                                const __hip_bfloat16* __restrict__ W2T,
                                                const float* __restrict__ a_src2,
                                                const float* __restrict__ a_dst2,
                                                float* __restrict__ h2,
                                                float* __restrict__ als2,
                                                float* __restrict__ ald2) {
  __shared__ __align__(16) unsigned char lds[33792];
  /* overlay 1 (ph1/ph2 input): xagg bf16 [H1][16][104] = 33,280 B   */
  /* overlay 2 (ph2 out/ph3 in): out1t bf16 [16][800]   = 25,600 B   */
  /* overlay 3 (ph3 out/ph4 in): h2t  fp32 [16][128] at +25600 = 8 KB */
  __hip_bfloat16* xbb = (__hip_bfloat16*)lds;
  __hip_bfloat16* out1t = (__hip_bfloat16*)lds;
  float* h2t = (float*)(lds + 25600);
#define XB(h, g, k) xbb[((h) * 16 + (g)) * 104 + (k)]

  int tid = threadIdx.x, wid = tid >> 6, lane = tid & 63;
  int n0 = blockIdx.x * 16;
  int col16 = lane & 15, kq = (lane >> 4) * 8;

  /* zero xagg (covers k 78..103 pad + unwritten lanes) */
  {
    unsigned int* p = (unsigned int*)lds;
    for (int i = tid; i < H1 * 16 * 52; i += 512) p[i] = 0u;
  }
  __syncthreads();

  /* ---- phase 1: per-wave weighted gather, 4-edge unroll ---- */
  #pragma unroll
  for (int rep = 0; rep < 2; ++rep) {
    int g = wid * 2 + rep;
    int n = n0 + g;
    int o = __builtin_amdgcn_readfirstlane(offs[n]);
    int d = __builtin_amdgcn_readfirstlane(deg[n]);
    float acc[H1], acc2[H1];
    #pragma unroll
    for (int h = 0; h < H1; ++h) { acc[h] = 0.f; acc2[h] = 0.f; }

    float onesel = (lane == 14) ? 1.0f : 0.f;
    int j = 0;
    for (; j + 4 <= d; j += 4) {
      int e0 = o + j;
      int s0 = src_s[e0], s1 = src_s[e0 + 1], s2 = src_s[e0 + 2], s3 = src_s[e0 + 3];
      const float* x0 = x + (size_t)s0 * F_IN;
      const float* x1 = x + (size_t)s1 * F_IN;
      const float* x2 = x + (size_t)s2 * F_IN;
      const float* x3 = x + (size_t)s3 * F_IN;
      float xa0 = x0[lane], xa1 = x1[lane], xa2 = x2[lane], xa3 = x3[lane];
      float xb0 = (lane < 14) ? x0[64 + lane] : onesel;
      float xb1 = (lane < 14) ? x1[64 + lane] : onesel;
      float xb2 = (lane < 14) ? x2[64 + lane] : onesel;
      float xb3 = (lane < 14) ? x3[64 + lane] : onesel;
      const float* wp = w1 + (size_t)e0 * H1;   /* 40 contiguous, uniform */
      #pragma unroll
      for (int h = 0; h < H1; ++h) {
        float wa = wp[h], wb = wp[10 + h], wc = wp[20 + h], wd = wp[30 + h];
        acc[h] = fmaf(wa, xa0, acc[h]);
        acc[h] = fmaf(wb, xa1, acc[h]);
        acc[h] = fmaf(wc, xa2, acc[h]);
        acc[h] = fmaf(wd, xa3, acc[h]);
        acc2[h] = fmaf(wa, xb0, acc2[h]);
        acc2[h] = fmaf(wb, xb1, acc2[h]);
        acc2[h] = fmaf(wc, xb2, acc2[h]);
        acc2[h] = fmaf(wd, xb3, acc2[h]);
      }
    }
    for (; j < d; ++j) {
      int e0 = o + j;
      int s0 = src_s[e0];
      const float* x0 = x + (size_t)s0 * F_IN;
      float xa0 = x0[lane];
      float xb0 = (lane < 14) ? x0[64 + lane] : onesel;
      const float* wp = w1 + (size_t)e0 * H1;
      #pragma unroll
      for (int h = 0; h < H1; ++h) {
        float wa = wp[h];
        acc[h] = fmaf(wa, xa0, acc[h]);
        acc2[h] = fmaf(wa, xb0, acc2[h]);
      }
    }
    #pragma unroll
    for (int h = 0; h < H1; ++h) {
      float inv = 1.f / __shfl(acc2[h], 14);
      XB(h, g, lane) = __float2bfloat16(acc[h] * inv);
      if (lane < 14) XB(h, g, 64 + lane) = __float2bfloat16(acc2[h] * inv);
    }
  }
  __syncthreads();

  /* ---- phase 2: 50 units (h, nt) over 8 waves; 3 MFMAs each ---- */
  const unsigned short* Bp1 = (const unsigned short*)W1T;
  v4f res[7];
  int nu = 0;
  for (int u = wid; u < 50; u += 8) {
    int h = u / 5, nt = u - (u / 5) * 5;
    v4f acc = (v4f){0.f, 0.f, 0.f, 0.f};
    #pragma unroll
    for (int kt = 0; kt < 3; ++kt) {
      v8s a = *reinterpret_cast<const v8s*>(&XB(h, col16, kt * 32 + kq));
      v8s b = *reinterpret_cast<const v8s*>(
          &Bp1[(size_t)(h * 78 + nt * 16 + col16) * K1P + kt * 32 + kq]);
      acc = __builtin_amdgcn_mfma_f32_16x16x32_bf16(a, b, acc, 0, 0, 0);
    }
    res[nu++] = acc;
  }
  __syncthreads();   /* all xagg reads done; LDS now reusable as out1t */

  /* tail-zero out1t cols 780..799 (disjoint from value stores) */
  if (tid < 160) {
    int node = tid / 10, cc = (tid - node * 10) * 2;
    *(unsigned int*)&out1t[node * 800 + 780 + cc] = 0u;
  }
  /* store phase-2 results (bias + ELU) into out1t */
  nu = 0;
  for (int u = wid; u < 50; u += 8) {
    int h = u / 5, nt = u - (u / 5) * 5;
    v4f acc = res[nu++];
    int cl = nt * 16 + col16;
    if (cl < 78) {
      int c = h * 78 + cl;
      float bv = b1[c];
      #pragma unroll
      for (int r = 0; r < 4; ++r) {
        int node = (lane >> 4) * 4 + r;
        float v = acc[r] + bv;
        v = (v > 0.f) ? v : expm1f(v);  /* ELU */
        out1t[node * 800 + c] = __float2bfloat16(v);
      }
    }
  }
  __syncthreads();

  /* ---- phase 3: h2 tile = out1t @ W2T^T; 1 unit (16 cols) per wave ---- */
  const unsigned short* Bp2 = (const unsigned short*)W2T;
  v4f acc3 = (v4f){0.f, 0.f, 0.f, 0.f};
  #pragma unroll 5
  for (int kt = 0; kt < 25; ++kt) {
    int k = kt * 32 + kq;
    v8s a = *reinterpret_cast<const v8s*>(&out1t[col16 * 800 + k]);
    v8s b = *reinterpret_cast<const v8s*>(&Bp2[(size_t)(wid * 16 + col16) * KP + k]);
    acc3 = __builtin_amdgcn_mfma_f32_16x16x32_bf16(a, b, acc3, 0, 0, 0);
  }
  {
    int col = wid * 16 + col16;
    #pragma unroll
    for (int r = 0; r < 4; ++r) {
      int node = (lane >> 4) * 4 + r;
      h2[(size_t)(n0 + node) * F_OUT + col] = acc3[r];
      h2t[node * F_OUT + col] = acc3[r];
    }
  }
  __syncthreads();

  /* ---- phase 4: layer-2 logits for this block's 16 nodes ---- */
  #pragma unroll
  for (int rep = 0; rep < 2; ++rep) {
    int nn = wid * 2 + rep;
    float v0 = h2t[nn * F_OUT + lane], v1 = h2t[nn * F_OUT + 64 + lane];
    float s = v0 * a_src2[lane] + v1 * a_src2[64 + lane];
    float dd = v0 * a_dst2[lane] + v1 * a_dst2[64 + lane];
    #pragma unroll
    for (int off = 32; off > 0; off >>= 1) {
      s += __shfl_down(s, off);
      dd += __shfl_down(dd, off);
    }
    if (lane == 0) { als2[n0 + nn] = s; ald2[n0 + nn] = dd; }
  }
#undef XB
}

/* ---- layer 2 aggregation (fused edge-weights, fp32 h2 gathers)
   + bias + ReLU + fused graph max-pool ---- */

__global__ __launch_bounds__(512) void k_agg2f(const float* __restrict__ h2,
                                               const float* __restrict__ als2,
                                               const float* __restrict__ ald2,
                                               const int* __restrict__ src_s,
                                               const int* __restrict__ offs,
                                               const int* __restrict__ deg,
                                               const float* __restrict__ b2,
                                               const int* __restrict__ batch,
                                               unsigned int* __restrict__ g) {
  int tid = threadIdx.x;
  int n = blockIdx.x * 4 + (tid >> 7);
  int f = tid & 127;
  int o = __builtin_amdgcn_readfirstlane(offs[n]);
  int d = __builtin_amdgcn_readfirstlane(deg[n]);
  float aldn = ald2[n];
  float acc = 0.f, ssum = 0.f;
  int j = 0;
  for (; j + 4 <= d; j += 4) {
    float wq[4], hq[4];
    #pragma unroll
    for (int q = 0; q < 4; ++q) {
      int e = o + j + q;
      int sb = src_s[e];
      float v = als2[sb] + aldn;
      v = (v > 0.f) ? v : NEG_SLOPE * v;
      wq[q] = __expf(v);
      hq[q] = h2[(size_t)sb * F_OUT + f];
    }
    #pragma unroll
    for (int q = 0; q < 4; ++q) {
      ssum += wq[q];
      acc = fmaf(wq[q], hq[q], acc);
    }
  }
  for (; j < d; ++j) {
    int e = o + j;
    int sb = src_s[e];
    float v = als2[sb] + aldn;
    v = (v > 0.f) ? v : NEG_SLOPE * v;
    float w = __expf(v);
    ssum += w;
    acc = fmaf(w, h2[(size_t)sb * F_OUT + f], acc);
  }
  float v = fmaxf(acc / ssum + b2[f], 0.f);
  int gc = __builtin_amdgcn_readfirstlane(batch[n]);
  atomicMax(&g[gc * F_OUT + f], __float_as_uint(v));
}

/* ---------------- fc ---------------- */

__global__ __launch_bounds__(128) void k_fc(const float* __restrict__ g,
                                            const float* __restrict__ fc_w,
                                            const float* __restrict__ fc_b,
                                            float* __restrict__ out) {
  int b = blockIdx.x, c = threadIdx.x;
  const float* gr = g + (size_t)b * F_OUT;
  float acc = 0.f;
  for (int k = 0; k < F_OUT; ++k) acc = fmaf(gr[k], fc_w[k * F_OUT + c], acc);
  float v = acc + fc_b[c];
  out[(size_t)b * F_OUT + c] = fmaxf(v, 0.f);
}

/* ---------------- launch ---------------- */

extern "C" void kernel_launch(void* const* d_in, const int* in_sizes, int n_in,
                              void* d_out, int out_size, void* d_ws, size_t ws_size,
                              hipStream_t stream) {
  const float* x      = (const float*)d_in[0];
  const int*   ei     = (const int*)  d_in[1];
  const int*   batch  = (const int*)  d_in[2];
  const float* W1     = (const float*)d_in[3];
  const float* a_src1 = (const float*)d_in[4];
  const float* a_dst1 = (const float*)d_in[5];
  const float* b1     = (const float*)d_in[6];
  const float* W2     = (const float*)d_in[7];
  const float* a_src2 = (const float*)d_in[8];
  const float* a_dst2 = (const float*)d_in[9];
  const float* b2     = (const float*)d_in[10];
  const float* fc_w   = (const float*)d_in[11];
  const float* fc_b   = (const float*)d_in[12];
  float* out = (float*)d_out;

  float* ws = (float*)d_ws;
  float* h2   = ws;                       /* 6,400,000 */
  float* als1 = ws + 6400000;             /*   500,000 */
  float* ald1 = ws + 6900000;             /*   500,000 */
  float* als2 = ws + 7400000;             /*    50,000 */
  float* ald2 = ws + 7450000;             /*    50,000 */
  float* g    = ws + 7500000;             /*    32,768 */
  float* was  = ws + 7533000;             /*       780 */
  float* wad  = ws + 7534000;             /*       780 */
  __hip_bfloat16* W2T = (__hip_bfloat16*)(ws + 7535000);  /* 102,400 bf16 */
  __hip_bfloat16* W1T = (__hip_bfloat16*)(ws + 7587000);  /*  76,800 bf16 */
  float* w1   = ws + 7626000;             /* 3,500,000 */
  int* ib     = (int*)(ws + 11126000);
  int* deg    = ib;                        /*  50,000 */
  int* offs   = ib + 50000;
  int* cursor = ib + 100000;
  int* src_s  = ib + 150000;               /* 350,000 */
  int* dst_s  = ib + 500000;               /* 350,000 */
  int* part   = ib + 850000;               /* 196 */
  int* ppref  = ib + 850224;               /* 196 */

  /* CSR build */
  hipMemsetAsync(deg, 0, N_NODES * sizeof(int), stream);
  k_deg<<<(E_TOT + 255) / 256, 256, 0, stream>>>(ei, deg);
  k_scan1<<<NB, 256, 0, stream>>>(deg, part);
  k_scan2<<<1, 64, 0, stream>>>(part, ppref);
  k_scan3<<<NB, 256, 0, stream>>>(deg, ppref, offs, cursor);
  k_scatter<<<(E_TOT + 255) / 256, 256, 0, stream>>>(ei, cursor, src_s, dst_s);

  /* weights prep */
  k_prep<<<4, 256, 0, stream>>>(W1, a_src1, a_dst1, was, wad);
  k_w1t<<<(800 * K1P + 255) / 256, 256, 0, stream>>>(W1, W1T);
  k_w2t<<<(F_OUT * KP + 255) / 256, 256, 0, stream>>>(W2, W2T);
  /* zero pool accumulator (used by fused agg2f) */
  hipMemsetAsync(g, 0, N_GRAPHS * F_OUT * sizeof(float), stream);

  /* layer 1 logits + edge weights */
  k_logits1<<<(N_NODES + 31) / 32, 320, 0, stream>>>(x, was, wad, als1, ald1);
  k_w1e<<<(E_TOT * H1 + 255) / 256, 256, 0, stream>>>(als1, ald1, src_s, dst_s, w1);

  /* mega-fused: agg1 + out1 + gemm2 + al2 */
  k_l12<<<N_NODES / 16, 512, 0, stream>>>(x, w1, src_s, offs, deg, W1T, b1,
                                          W2T, a_src2, a_dst2, h2, als2, ald2);

  /* layer 2 (edge weights fused into agg2f) */
  k_agg2f<<<(N_NODES + 3) / 4, 512, 0, stream>>>(h2, als2, ald2, src_s, offs, deg,
                                                 b2, batch, (unsigned int*)g);

  /* fc */
  k_fc<<<N_GRAPHS, F_OUT, 0, stream>>>(g, fc_w, fc_b, out);
}